// Round 11
// baseline (97.276 us; speedup 1.0000x reference)
//
#include <hip/hip_runtime.h>

typedef unsigned long long u64;

__device__ __forceinline__ int find_root(int* L, int a){
    int p = L[a];
    while(p != a){
        int gp = L[p];
        if(gp != p) L[a] = gp;   // path halving; benign race
        a = p; p = gp;
    }
    return a;
}

// Link-by-index (root hi -> lo): links strictly decrease => acyclic under
// concurrency. Every successful CAS merges exactly two distinct trees =>
// components = nodes - sum(successes).
__device__ __forceinline__ int unite(int* L, int a, int b){
    while(true){
        a = find_root(L, a);
        b = find_root(L, b);
        if(a == b) return 0;
        int hi = (a > b) ? a : b;
        int lo = (a > b) ? b : a;
        int old = atomicCAS(&L[hi], hi, lo);
        if(old == hi) return 1;
        a = old; b = lo;
    }
}

// One block per (ch,threshold,region,strip-half): R8's bitmask-run CCL on a
// 64-row strip (128 u64 words, thread==word). Outputs per strip: pix, edges,
// partial b0 (=runs-merges), boundary-row masks, boundary run root labels.
__global__ __launch_bounds__(128) void ccl_half(const float* __restrict__ prob,
                                                const int*   __restrict__ sel,
                                                int*   __restrict__ labs,   // [1600][64]
                                                u64*   __restrict__ bmask,  // [1600][2]
                                                int*   __restrict__ stats,  // [1600][3]
                                                float* __restrict__ out){
    __shared__ u64 M[128];     // strip row masks: word w = (lrow<<1)|half
    __shared__ u64 S[128];     // run-start masks
    __shared__ int Pr[129];    // exclusive prefix of per-word run counts
    __shared__ int L[4096];    // union-find arena (16 KB); R <= 64 rows * 64 runs
    __shared__ int red[8];
    const int tid = threadIdx.x, bid = blockIdx.x;
    if(bid == 0 && tid == 0) atomicExch(out, 0.0f);    // zero for rows' atomicAdd
    const int ib = bid >> 1, h = bid & 1;              // image-problem, strip half
    const int ch = ib / 400, t = (ib % 400) >> 2, r = ib & 3;
    const float th = (float)t / 99.0f;
    const float* img = prob + (size_t)(sel[r] * 3 + ch) * 16384;
    const float4* imgv = (const float4*)img + h * 2048;   // 64 rows * 32 f4/row

    // per-thread word build: thread w owns strip pixels [64w, 64w+64)
    const int w = tid;
    {
        u64 mw = 0ULL;
        #pragma unroll
        for(int k = 0; k < 16; k++){
            const float4 v = imgv[w * 16 + k];
            const unsigned nib = (unsigned)(v.x > th)
                               | ((unsigned)(v.y > th) << 1)
                               | ((unsigned)(v.z > th) << 2)
                               | ((unsigned)(v.w > th) << 3);
            mw |= (u64)nib << (4 * k);
        }
        M[w] = mw;
    }
    __syncthreads();                                   // B1: M complete

    const int lane = tid & 63, wave = tid >> 6;        // 2 waves
    const int lrow = w >> 1, half = w & 1;
    const u64 m = M[w];
    const u64 lcar = half ? (M[w - 1] >> 63) : 0ULL;
    const u64 s = m & ~((m << 1) | lcar);
    S[w] = s;
    int pix   = __popcll(m);
    int edges = __popcll(m & ((m << 1) | lcar));       // horizontal pairs
    const u64 va = (lrow > 0) ? M[w - 2] : 0ULL;
    edges += __popcll(m & va);                          // vertical pairs (in-strip)
    const int runs = __popcll(s);
    u64 csm = 0ULL;
    if(lrow > 0){
        const u64 c = m & va;
        const u64 ccar = half ? ((M[w - 1] & M[w - 3]) >> 63) : 0ULL;
        csm = c & ~((c << 1) | ccar);                   // contact-segment starts
    }

    // prefix sum of runs over 128 words -> compact run ids
    int incl = runs;
    for(int off = 1; off < 64; off <<= 1){
        int n = __shfl_up(incl, off, 64);
        if(lane >= off) incl += n;
    }
    if(lane == 63) red[wave] = incl;
    __syncthreads();                                   // B2
    const int woff = wave ? red[0] : 0;
    const int excl = woff + incl - runs;
    Pr[w] = excl;
    if(w == 127) Pr[128] = excl + runs;
    const u64 sa = (lrow > 0) ? S[w - 2] : 0ULL;
    __syncthreads();                                   // B3: Pr complete
    const int R = Pr[128];
    const int Pa = (lrow > 0) ? Pr[w - 2] : 0;

    {   // arena init: only R live nodes
        int4* L4 = (int4*)L;
        const int n4 = (R + 3) >> 2;
        for(int i = tid; i < n4; i += 128){ int b = i * 4; L4[i] = make_int4(b, b+1, b+2, b+3); }
    }
    __syncthreads();                                   // B4: arena ready

    int merges = 0;
    {
        u64 cs = csm;
        while(cs){
            const int x = __ffsll(cs) - 1;
            cs &= cs - 1;
            const u64 lm = (2ULL << x) - 1;
            const int nb = excl + __popcll(s  & lm) - 1;
            const int na = Pa   + __popcll(sa & lm) - 1;
            merges += unite(L, na, nb);
        }
    }
    __syncthreads();                                   // B5: unions complete

    // boundary run labels: h==0 -> last row, ids [Pr[126],R); h==1 -> first row, ids [0,Pr[2])
    {
        const int lo    = h ? 0 : Pr[126];
        const int hiEnd = h ? Pr[2] : R;
        for(int i = lo + tid; i < hiEnd; i += 128)
            labs[(size_t)bid * 64 + (i - lo)] = find_root(L, i);
        if(tid < 2){
            const int bw = h ? tid : (126 + tid);      // boundary row's two words
            bmask[(size_t)bid * 2 + tid] = M[bw];
        }
    }

    int v0 = pix, v1 = edges, v2 = merges;
    for(int off = 32; off; off >>= 1){
        v0 += __shfl_down(v0, off, 64);
        v1 += __shfl_down(v1, off, 64);
        v2 += __shfl_down(v2, off, 64);
    }
    __syncthreads();                                   // red[] reusable
    if(lane == 0){ red[wave*3] = v0; red[wave*3+1] = v1; red[wave*3+2] = v2; }
    __syncthreads();
    if(tid == 0){
        stats[(size_t)bid*3 + 0] = red[0] + red[3];            // pix
        stats[(size_t)bid*3 + 1] = red[1] + red[4];            // edges (in-strip)
        stats[(size_t)bid*3 + 2] = R - (red[2] + red[5]);      // strip b0
    }
}

// One block (1 wave) per (ch,t,r): union strip-components across the seam.
// Arena keyed by label (top) / label+4096 (bottom); only present labels init'd.
__global__ __launch_bounds__(64) void merge_kernel(const int* __restrict__ labs,
                                                   const u64* __restrict__ bmask,
                                                   const int* __restrict__ stats,
                                                   float*     __restrict__ betti){
    __shared__ int A[8192];
    __shared__ int TL[64], BL[64];
    const int ib = blockIdx.x, tid = threadIdx.x;
    const int tb = ib * 2, bb = ib * 2 + 1;
    const u64 t0 = bmask[(size_t)tb*2], t1 = bmask[(size_t)tb*2+1];
    const u64 b0m = bmask[(size_t)bb*2], b1m = bmask[(size_t)bb*2+1];
    const u64 st0 = t0 & ~(t0 << 1);
    const u64 st1 = t1 & ~((t1 << 1) | (t0 >> 63));
    const u64 sb0 = b0m & ~(b0m << 1);
    const u64 sb1 = b1m & ~((b1m << 1) | (b0m >> 63));
    const int nT = __popcll(st0) + __popcll(st1);
    const int nB = __popcll(sb0) + __popcll(sb1);
    if(tid < nT) TL[tid] = labs[(size_t)tb*64 + tid];
    if(tid < nB) BL[tid] = labs[(size_t)bb*64 + tid];
    __syncthreads();
    if(tid < nT){ const int l = TL[tid];        A[l] = l; }
    if(tid < nB){ const int l = BL[tid] + 4096; A[l] = l; }
    __syncthreads();

    const u64 c0 = t0 & b0m, c1 = t1 & b1m;
    const u64 cs0 = c0 & ~(c0 << 1);
    const u64 cs1 = c1 & ~((c1 << 1) | (c0 >> 63));
    const int n0 = __popcll(cs0), nC = n0 + __popcll(cs1);
    const int seamE = __popcll(c0) + __popcll(c1);

    int merges = 0;
    for(int j = tid; j < nC; j += 64){
        u64 cs; int k, wv;
        if(j < n0){ cs = cs0; wv = 0; k = j; } else { cs = cs1; wv = 1; k = j - n0; }
        for(int q = 0; q < k; q++) cs &= cs - 1;       // select k-th set bit
        const int x = __ffsll(cs) - 1;
        const u64 lm = (2ULL << x) - 1;
        int it, ibx;
        if(wv == 0){ it = __popcll(st0 & lm) - 1;                 ibx = __popcll(sb0 & lm) - 1; }
        else       { it = __popcll(st0) + __popcll(st1 & lm) - 1; ibx = __popcll(sb0) + __popcll(sb1 & lm) - 1; }
        merges += unite(A, TL[it], BL[ibx] + 4096);
    }
    for(int off = 32; off; off >>= 1) merges += __shfl_down(merges, off, 64);
    if(tid == 0){
        const int pix   = stats[(size_t)tb*3]   + stats[(size_t)bb*3];
        const int edges = stats[(size_t)tb*3+1] + stats[(size_t)bb*3+1] + seamE;
        const int b0    = stats[(size_t)tb*3+2] + stats[(size_t)bb*3+2] - merges;
        const int ch = ib / 400, t = (ib % 400) >> 2, r = ib & 3;
        const float b0f = (float)b0;
        const float b1f = b0f - ((float)pix - (float)edges);
        const size_t o = (((size_t)ch * 100 + t) * 4 + r) * 2;
        betti[o] = b0f; betti[o + 1] = b1f;
    }
}

// One block per (region, code-column) row; accumulates into out[0]
// (zeroed by ccl_half block 0) with a device-scope float atomicAdd.
__global__ __launch_bounds__(128) void rows_kernel(const float* __restrict__ betti,
                                                   const float* __restrict__ gt,
                                                   float*       __restrict__ out){
    __shared__ float codes[100];
    __shared__ float birth[99], bs0[99], bs1[99], gs0[99], gs1[99];
    __shared__ float gsh[198];
    __shared__ float red[4];
    const int row = blockIdx.x;          // r*6 + j
    const int r = row / 6, j = row % 6;
    const int chmap[6] = {0, 0, 1, 1, 0, 0};   // inside, boundary, union(=inside)
    const int ch = chmap[j], comp = j & 1;
    const int tid = threadIdx.x;

    if(tid < 100) codes[tid] = betti[(((size_t)ch * 100 + tid) * 4 + r) * 2 + comp];
    const float* g = gt + (size_t)row * 99 * 2;
    for(int i = tid; i < 198; i += 128) gsh[i] = g[i];
    __syncthreads();

    float b = 0.f, d = 0.f;
    if(tid < 99){
        const float dv = codes[tid + 1] - codes[tid];
        const float thv = (float)tid / 99.0f;
        b = (dv > 0.f) ? thv : 0.f;
        d = (dv < 0.f) ? thv : 0.f;
        birth[tid] = b;
    }
    __syncthreads();

    if(tid < 99){
        // stable sort by birth == stable partition (positive births already ascending)
        int zb = 0, tz = 0;
        for(int k = 0; k < 99; k++){
            const int z = (birth[k] == 0.f) ? 1 : 0;
            tz += z;
            if(k < tid) zb += z;
        }
        const int pos = (b == 0.f) ? zb : (tz + tid - zb);
        bs0[pos] = b; bs1[pos] = d;

        const float gb = gsh[tid * 2];
        int rank = 0;
        for(int k = 0; k < 99; k++){
            const float o = gsh[k * 2];
            rank += (o < gb || (o == gb && k < tid)) ? 1 : 0;
        }
        gs0[rank] = gb; gs1[rank] = gsh[tid * 2 + 1];
    }
    __syncthreads();

    float mm = 0.f, u = 0.f;
    if(tid < 99){
        mm = fabsf(bs0[tid] - gs0[tid]) + fabsf(bs1[tid] - gs1[tid]);
        u = d - b;
    }
    for(int off = 32; off; off >>= 1){
        mm += __shfl_down(mm, off, 64);
        u  += __shfl_down(u,  off, 64);
    }
    if((tid & 63) == 0){ red[(tid >> 6)*2] = mm; red[(tid >> 6)*2 + 1] = u; }
    __syncthreads();
    if(tid == 0)
        atomicAdd(out, (red[0] + red[2]) / 2376.0f + (red[1] + red[3]) / 24.0f);
}

extern "C" void kernel_launch(void* const* d_in, const int* in_sizes, int n_in,
                              void* d_out, int out_size, void* d_ws, size_t ws_size,
                              hipStream_t stream){
    const float* prob = (const float*)d_in[0];   // [4,3,128,128] f32
    const int*   sel  = (const int*)d_in[1];     // [4]
    const float* gt   = (const float*)d_in[2];   // [4,6,99,2] f32
    float* betti = (float*)d_ws;                 // [2][100][4][2] = 1600 floats
    int*   wsI   = (int*)d_ws;
    int*   labs  = wsI + 2048;                   // [1600][64] ints
    u64*   bmask = (u64*)(wsI + 104448);         // [1600][2] u64 (8B-aligned)
    int*   stats = wsI + 110848;                 // [1600][3] ints

    ccl_half    <<<1600, 128, 0, stream>>>(prob, sel, labs, bmask, stats, (float*)d_out);
    merge_kernel<<<800, 64, 0, stream>>>(labs, bmask, stats, betti);
    rows_kernel <<<24, 128, 0, stream>>>(betti, gt, (float*)d_out);
}